// Round 3
// baseline (63.994 us; speedup 1.0000x reference)
//
#include <hip/hip_runtime.h>
#include <hip/hip_bf16.h>

#define G 32
#define NNBR 16
#define ATOM_TYPE 6

// Block: 256 threads. Grid: (B*A=128, G=32). Each block handles one (b,a) pair
// and ONE i-plane (32*32 = 1024 voxels = 256 float4 -> 1 float4/thread).
// With i fixed per block, Ex[m][i] is folded into the Ey table at fill time:
// sP[m][j] = exp(coeff*((ti-dx)^2 + (tj-dy)^2)), so the inner loop is
// acc4 += sP[m][j] * sEz[m][k0..k0+3] -- 1 b32 + 1 b128 LDS read + 4 FMA per m.
__global__ __launch_bounds__(256) void voxel_kernel(
    const float* __restrict__ dv,     // (B=4, A=32, N=16, 3)
    const int*   __restrict__ an,     // (A=32, N=16) int32
    const float* __restrict__ sigma,  // (1,)
    float*       __restrict__ out)    // (B, A, G, G, G)
{
    const int ba  = blockIdx.x;        // b*32 + a
    const int a   = ba & 31;
    const int i   = blockIdx.y;        // 0..31
    const int tid = threadIdx.x;

    __shared__ __align__(16) float sP [NNBR][G];   // Ex[i]*Ey[j], compacted m
    __shared__ __align__(16) float sEz[NNBR][G];
    __shared__ float sDv[NNBR * 3];
    __shared__ int   sIdx[NNBR];
    __shared__ int   sM;

    // Prefetch distance vectors (48 floats), parallel with the an load.
    if (tid < NNBR * 3) sDv[tid] = dv[(size_t)ba * (NNBR * 3) + tid];

    // Parallel mask compaction: ballot + popcount prefix (wave 0 does the work).
    int flag = 0;
    if (tid < NNBR) flag = (an[a * NNBR + tid] == ATOM_TYPE) ? 1 : 0;
    unsigned long long mask = __ballot(flag);
    if (flag) {
        int pos = __popcll(mask & ((1ull << tid) - 1ull));
        sIdx[pos] = tid;
    }
    if (tid == 0) sM = (int)__popcll(mask);
    __syncthreads();

    const int   M     = sM;
    const float s     = sigma[0];
    const float coeff = -0.5f / (s * s);
    const float step  = 8.0f / 31.0f;          // linspace(-4,4,32) spacing
    const float ti    = -4.0f + (float)i * step;

    // Fill fused P = Ex*Ey and Ez tables (M*32 <= 512 items, 2 exps each).
    for (int idx = tid; idx < M * G; idx += 256) {
        const int m = idx >> 5;
        const int j = idx & 31;
        const int n = sIdx[m];
        const float tj  = -4.0f + (float)j * step;
        const float dxv = ti - sDv[3 * n + 0];
        const float dyv = tj - sDv[3 * n + 1];
        const float dzv = tj - sDv[3 * n + 2];
        sP [m][j] = __expf(coeff * (dxv * dxv + dyv * dyv));
        sEz[m][j] = __expf(coeff * (dzv * dzv));
    }
    __syncthreads();

    const int j  = tid >> 3;            // 0..31
    const int k0 = (tid & 7) << 2;      // 0,4,...,28

    float4 acc = {0.f, 0.f, 0.f, 0.f};
    for (int m = 0; m < M; ++m) {
        const float  p  = sP[m][j];                      // broadcast read
        const float4 ez = *(const float4*)&sEz[m][k0];   // ds_read_b128
        acc.x += p * ez.x;
        acc.y += p * ez.y;
        acc.z += p * ez.z;
        acc.w += p * ez.w;
    }

    // One coalesced float4 store per thread: block covers a dense 4 KB plane.
    float4* out4 = (float4*)(out + ((size_t)ba * G + i) * (G * G));
    out4[tid] = acc;
}

extern "C" void kernel_launch(void* const* d_in, const int* in_sizes, int n_in,
                              void* d_out, int out_size, void* d_ws, size_t ws_size,
                              hipStream_t stream) {
    const float* dv    = (const float*)d_in[0];   // (4,32,16,3)
    const int*   an    = (const int*)d_in[1];     // (32,16)
    const float* sigma = (const float*)d_in[2];   // (1,)
    float*       out   = (float*)d_out;           // (4,32,32,32,32)

    dim3 grid(4 * 32, G);
    dim3 block(256);
    voxel_kernel<<<grid, block, 0, stream>>>(dv, an, sigma, out);
}